// Round 1
// baseline (210.413 us; speedup 1.0000x reference)
//
#include <hip/hip_runtime.h>
#include <stdint.h>

#define SEQL 4096
#define NHEAD 8
#define DHEAD 64
#define DPROJ 512
#define HEADELEMS (SEQL * DHEAD)  // 262144

typedef unsigned short u16;
typedef __bf16 bf16x8 __attribute__((ext_vector_type(8)));
typedef float f32x4 __attribute__((ext_vector_type(4)));

__device__ __forceinline__ u16 f2bf(float f) {
  union { float f; uint32_t u; } x; x.f = f;
  uint32_t r = x.u + 0x7fffu + ((x.u >> 16) & 1u);
  return (u16)(r >> 16);
}

// ---------------- Projection: P = (X @ W + b) * scale  -> bf16 flat --------
// X: [4096, 64] f32; W: [64, 512] f32 row-major; b: [512]; P: [4096, 512] bf16.
// blockIdx.y selects q/k/v; q gets the 1/sqrt(d)=0.125 score scale folded in.
__global__ __launch_bounds__(256) void proj_kernel(
    const float* __restrict__ q, const float* __restrict__ k, const float* __restrict__ v,
    const float* __restrict__ qw, const float* __restrict__ qb,
    const float* __restrict__ kw, const float* __restrict__ kb,
    const float* __restrict__ vw, const float* __restrict__ vb,
    u16* __restrict__ Qp, u16* __restrict__ Kp, u16* __restrict__ Vp) {
  const float* X; const float* W; const float* B; u16* P; float scale;
  if (blockIdx.y == 0)      { X = q; W = qw; B = qb; P = Qp; scale = 0.125f; }
  else if (blockIdx.y == 1) { X = k; W = kw; B = kb; P = Kp; scale = 1.0f; }
  else                      { X = v; W = vw; B = vb; P = Vp; scale = 1.0f; }

  __shared__ float xs[16][64];
  const int t = threadIdx.x;
  const int rowbase = blockIdx.x * 16;
  for (int i = t; i < 16 * 64; i += 256) xs[i >> 6][i & 63] = X[rowbase * 64 + i];
  __syncthreads();

  const int c0 = t * 2;
  float acc0[16] = {}, acc1[16] = {};
  for (int kk = 0; kk < 64; ++kk) {
    const float2 w = *(const float2*)(W + kk * 512 + c0);
    #pragma unroll
    for (int r = 0; r < 16; ++r) {
      const float x = xs[r][kk];
      acc0[r] = fmaf(x, w.x, acc0[r]);
      acc1[r] = fmaf(x, w.y, acc1[r]);
    }
  }
  const float b0 = B[c0], b1 = B[c0 + 1];
  #pragma unroll
  for (int r = 0; r < 16; ++r) {
    const u16 o0 = f2bf((acc0[r] + b0) * scale);
    const u16 o1 = f2bf((acc1[r] + b1) * scale);
    *(uint32_t*)(P + (rowbase + r) * 512 + c0) = ((uint32_t)o1 << 16) | (uint32_t)o0;
  }
}

// ---------------- V-head transpose: vhT[h][dd][s] = Vp[h][s][dd] -----------
__global__ __launch_bounds__(256) void vtrans_kernel(const u16* __restrict__ Vp,
                                                     u16* __restrict__ vhT) {
  const int h = blockIdx.y;
  const int s0 = blockIdx.x * 64;
  __shared__ u16 tile[64][65];
  const int t = threadIdx.x;
  const u16* __restrict__ src = Vp + h * HEADELEMS;
  for (int i = t; i < 64 * 64; i += 256) {
    const int si = i >> 6, dd = i & 63;
    tile[dd][si] = src[(s0 + si) * 64 + dd];
  }
  __syncthreads();
  u16* __restrict__ dst = vhT + h * HEADELEMS;
  for (int o = t; o < 64 * 64; o += 256) {
    const int dd = o >> 6, si = o & 63;
    dst[dd * 4096 + s0 + si] = tile[dd][si];
  }
}

// ---------------- Flash attention (bf16 MFMA, fp32 softmax/accum) ----------
// Block: 4 waves x 16 q-rows = 64 q-rows. Loop over 64-key tiles.
// MFMA 16x16x32 layouts: A/B lane l: row/col = l&15, k = (l>>4)*8+j.
//                        C/D lane l: col = l&15, row = (l>>4)*4 + reg.
__global__ __launch_bounds__(256) void attn_kernel(
    const u16* __restrict__ Qp, const u16* __restrict__ Kp,
    const u16* __restrict__ vhT, float* __restrict__ ctx) {
  const int h = blockIdx.y;
  const int qblk = blockIdx.x;
  const int t = threadIdx.x;
  const int wave = t >> 6;
  const int lane = t & 63;
  const int l16 = lane & 15;
  const int lhi = lane >> 4;

  // +8 u16 row pad -> 144B row stride (16B aligned, breaks same-bank stride)
  __shared__ __align__(16) u16 klds[64][72];
  __shared__ __align__(16) u16 vtlds[64][72];
  __shared__ __align__(16) u16 plds[4][16][72];

  const u16* __restrict__ Qh = Qp + h * HEADELEMS;
  const u16* __restrict__ Kh = Kp + h * HEADELEMS;
  const u16* __restrict__ VTh = vhT + h * HEADELEMS;

  const int qrow = qblk * 64 + wave * 16 + l16;
  const bf16x8 qf0 = *(const bf16x8*)(Qh + qrow * 64 + lhi * 8);
  const bf16x8 qf1 = *(const bf16x8*)(Qh + qrow * 64 + 32 + lhi * 8);

  const f32x4 zero4 = {0.f, 0.f, 0.f, 0.f};
  f32x4 cacc[4];
  #pragma unroll
  for (int i = 0; i < 4; ++i) cacc[i] = zero4;
  float mrow[4], lsum[4];
  #pragma unroll
  for (int r = 0; r < 4; ++r) { mrow[r] = -__builtin_inff(); lsum[r] = 0.f; }

  for (int kt = 0; kt < SEQL / 64; ++kt) {
    __syncthreads();
    // stage K tile [64 keys][64 d] and V^T tile [64 d][64 keys], 16B chunks
    #pragma unroll
    for (int rep = 0; rep < 2; ++rep) {
      const int cid = t + rep * 256;
      const int row = cid >> 3, cc = (cid & 7) * 8;
      *(uint4*)(&klds[row][cc]) = *(const uint4*)(Kh + (kt * 64 + row) * 64 + cc);
      *(uint4*)(&vtlds[row][cc]) = *(const uint4*)(VTh + row * 4096 + kt * 64 + cc);
    }
    __syncthreads();

    // QK^T: S[q, key], 4 key-fragments of 16
    f32x4 sacc[4];
    #pragma unroll
    for (int f = 0; f < 4; ++f) {
      f32x4 a = zero4;
      const bf16x8 kf0 = *(const bf16x8*)(&klds[f * 16 + l16][lhi * 8]);
      const bf16x8 kf1 = *(const bf16x8*)(&klds[f * 16 + l16][32 + lhi * 8]);
      a = __builtin_amdgcn_mfma_f32_16x16x32_bf16(qf0, kf0, a, 0, 0, 0);
      a = __builtin_amdgcn_mfma_f32_16x16x32_bf16(qf1, kf1, a, 0, 0, 0);
      sacc[f] = a;
    }

    // online softmax; each lane tracks rows lhi*4+r, reduce over 16 key-lanes
    float pp[4][4];
    #pragma unroll
    for (int r = 0; r < 4; ++r) {
      float mt = fmaxf(fmaxf(sacc[0][r], sacc[1][r]), fmaxf(sacc[2][r], sacc[3][r]));
      mt = fmaxf(mt, __shfl_xor(mt, 1));
      mt = fmaxf(mt, __shfl_xor(mt, 2));
      mt = fmaxf(mt, __shfl_xor(mt, 4));
      mt = fmaxf(mt, __shfl_xor(mt, 8));
      const float mnew = fmaxf(mrow[r], mt);
      const float alpha = __expf(mrow[r] - mnew);
      mrow[r] = mnew;
      float ps = 0.f;
      #pragma unroll
      for (int f = 0; f < 4; ++f) {
        const float p = __expf(sacc[f][r] - mnew);
        pp[f][r] = p;
        ps += p;
      }
      ps += __shfl_xor(ps, 1);
      ps += __shfl_xor(ps, 2);
      ps += __shfl_xor(ps, 4);
      ps += __shfl_xor(ps, 8);
      lsum[r] = lsum[r] * alpha + ps;
      #pragma unroll
      for (int f2 = 0; f2 < 4; ++f2) cacc[f2][r] *= alpha;
    }

    // P -> bf16 -> per-wave LDS (re-layout C/D frag -> A-operand frag)
    #pragma unroll
    for (int f = 0; f < 4; ++f)
      #pragma unroll
      for (int r = 0; r < 4; ++r)
        plds[wave][lhi * 4 + r][f * 16 + l16] = f2bf(pp[f][r]);

    // PV: ctx[q, dd] += P[q, keys] @ V[keys, dd]
    #pragma unroll
    for (int ks = 0; ks < 2; ++ks) {
      const bf16x8 pf = *(const bf16x8*)(&plds[wave][l16][ks * 32 + lhi * 8]);
      #pragma unroll
      for (int f2 = 0; f2 < 4; ++f2) {
        const bf16x8 vf = *(const bf16x8*)(&vtlds[f2 * 16 + l16][ks * 32 + lhi * 8]);
        cacc[f2] = __builtin_amdgcn_mfma_f32_16x16x32_bf16(pf, vf, cacc[f2], 0, 0, 0);
      }
    }
  }

  // epilogue: normalize, write fp32 ctx in flat [h, S, d] order
  const int qr0 = qblk * 64 + wave * 16 + lhi * 4;
  #pragma unroll
  for (int f2 = 0; f2 < 4; ++f2)
    #pragma unroll
    for (int r = 0; r < 4; ++r)
      ctx[h * HEADELEMS + (qr0 + r) * 64 + f2 * 16 + l16] = cacc[f2][r] / lsum[r];
}

// ---------------- Output projection: out = ctx2 @ ow_w + ow_b (fp32) -------
// ctx viewed flat as [4096, 512]; W: [512, 64]; out: [4096, 64]
__global__ __launch_bounds__(256) void outproj_kernel(
    const float* __restrict__ ctx, const float* __restrict__ W,
    const float* __restrict__ B, float* __restrict__ out) {
  const int t = threadIdx.x;
  const int col = t & 63;
  const int rowbase = blockIdx.x * 16 + (t >> 6) * 4;
  float acc[4] = {0.f, 0.f, 0.f, 0.f};
  #pragma unroll 4
  for (int kk = 0; kk < 512; ++kk) {
    const float w = W[kk * 64 + col];
    #pragma unroll
    for (int j = 0; j < 4; ++j)
      acc[j] = fmaf(ctx[(rowbase + j) * 512 + kk], w, acc[j]);
  }
  const float b = B[col];
  #pragma unroll
  for (int j = 0; j < 4; ++j) out[(rowbase + j) * 64 + col] = acc[j] + b;
}

extern "C" void kernel_launch(void* const* d_in, const int* in_sizes, int n_in,
                              void* d_out, int out_size, void* d_ws, size_t ws_size,
                              hipStream_t stream) {
  const float* q  = (const float*)d_in[0];
  const float* k  = (const float*)d_in[1];
  const float* v  = (const float*)d_in[2];
  const float* qw = (const float*)d_in[3];
  const float* qb = (const float*)d_in[4];
  const float* kw = (const float*)d_in[5];
  const float* kb = (const float*)d_in[6];
  const float* vw = (const float*)d_in[7];
  const float* vb = (const float*)d_in[8];
  const float* ow = (const float*)d_in[9];
  const float* ob = (const float*)d_in[10];

  char* ws = (char*)d_ws;
  u16* Qp   = (u16*)(ws);                    // 4 MB bf16 [4096,512] (pre-scaled 1/8)
  u16* Kp   = (u16*)(ws + (4u << 20));       // 4 MB
  u16* Vp   = (u16*)(ws + (8u << 20));       // 4 MB
  u16* vhT  = (u16*)(ws + (12u << 20));      // 4 MB bf16 [8][64][4096]
  float* cx = (float*)(ws + (16u << 20));    // 8 MB fp32 ctx flat [h,S,d]
  float* out = (float*)d_out;

  proj_kernel<<<dim3(SEQL / 16, 3), 256, 0, stream>>>(q, k, v, qw, qb, kw, kb, vw, vb,
                                                      Qp, Kp, Vp);
  vtrans_kernel<<<dim3(SEQL / 64, NHEAD), 256, 0, stream>>>(Vp, vhT);
  attn_kernel<<<dim3(SEQL / 64, NHEAD), 256, 0, stream>>>(Qp, Kp, vhT, cx);
  outproj_kernel<<<SEQL / 16, 256, 0, stream>>>(cx, ow, ob, out);
}